// Round 12
// baseline (296.651 us; speedup 1.0000x reference)
//
#include <hip/hip_runtime.h>

#define NBATCH 16
#define MAXB 256
#define BS 16
#define HQ 32
#define HKV 8
#define G 4
#define HD 128
#define SCALE 0.08838834764831845f
#define NEGF -1.0e30f   // running-max init
#define NEGI -2.0e30f   // invalid-position score: exp(NEGI - m) == 0 for any m >= NEGF
#define RESCALE_THR 8.0f
#define NSPLIT 32       // per-seq splits: per = 64..128 positions -> all splits active

__device__ __forceinline__ float dot8(const float4 a0, const float4 a1,
                                      const float4 b0, const float4 b1) {
  return a0.x*b0.x + a0.y*b0.y + a0.z*b0.z + a0.w*b0.w +
         a1.x*b1.x + a1.y*b1.y + a1.z*b1.z + a1.w*b1.w;
}

// 16-lane DPP row reduction — pure VALU (DS-pipe shuffles were the r1-r4 limit)
template<int CTL>
__device__ __forceinline__ float dpp_row_add(float v) {
  const int s = __builtin_amdgcn_update_dpp(0, __float_as_int(v), CTL, 0xF, 0xF, true);
  return v + __int_as_float(s);
}
__device__ __forceinline__ float row_reduce_add(float v) {
  v = dpp_row_add<0x128>(v);  // row_ror:8
  v = dpp_row_add<0x124>(v);  // row_ror:4
  v = dpp_row_add<0x122>(v);  // row_ror:2
  v = dpp_row_add<0x121>(v);  // row_ror:1
  return v;                   // all 16 lanes of the row hold the sum
}

// Workgroup = (split, b, hg): 256 threads = 4 waves, wave w = kv-head hg*4+w.
// r9's verbatim 105us structure (rotating 4-buffer reg pipeline, chunked dim
// map, DPP reduce, defer-max) + FUSED final reduction: after the partial
// write, device-release fence + per-(b,hg) atomic counter; the last block of
// each (b,hg) reduces all NSPLIT partials for its 16 q-heads straight to
// d_out while they are cache-warm. Removes the pa_reduce dispatch + its
// launch gap + the cold 8.5MB partial re-read (~15us of the 105 total).
// r8/r11 lesson: LDS/barrier staging costs +45us -> stay reg-staged.
__global__ __launch_bounds__(256) void pa_split(
    const float* __restrict__ q,
    const float* __restrict__ knew,
    const float* __restrict__ vnew,
    const float* __restrict__ k_cache,
    const float* __restrict__ v_cache,
    const int* __restrict__ block_tables,
    const int* __restrict__ seq_lens,
    int*   __restrict__ cnt,       // [NBATCH*2] arrival counters (zeroed per launch)
    float* __restrict__ part_ml,   // [B][HKV][NSPLIT][G][2]
    float* __restrict__ part_acc,  // [B][HKV][NSPLIT][G][HD]
    float* __restrict__ out)       // [B][HQ][HD]
{
  const int hg    = blockIdx.x & 1;
  const int b     = (blockIdx.x >> 1) % NBATCH;    // batch-minor: balance
  const int split = blockIdx.x / (2 * NBATCH);
  const int h     = hg * 4 + (threadIdx.x >> 6);
  const int lane  = threadIdx.x & 63;
  const int tg    = lane >> 4;
  const int tl    = lane & 15;

  const int seq_len = seq_lens[b];
  int per = (seq_len + NSPLIT - 1) / NSPLIT;
  per = (per + 15) & ~15;                          // page-align (64 or 128)
  const int s0 = split * per;
  const int s1 = min(seq_len, s0 + per);
  const int last = seq_len - 1;
  const size_t pidx = (size_t)(b*HKV + h)*NSPLIT + split;

  // ---- q fragments, chunked dim map: lane owns dims {tl*4..+3, 64+tl*4..+3}
  float4 q0[G], q1[G];
#pragma unroll
  for (int j = 0; j < G; ++j) {
    const float* qp = q + (size_t)(b*HQ + h*G + j)*HD;
    q0[j] = *(const float4*)(qp + tl*4);
    q1[j] = *(const float4*)(qp + 64 + tl*4);
  }

  float m[G], l[G];
  float4 a0[G], a1[G];
#pragma unroll
  for (int j = 0; j < G; ++j) {
    m[j] = NEGF; l[j] = 0.f;
    a0[j] = make_float4(0.f,0.f,0.f,0.f);
    a1[j] = make_float4(0.f,0.f,0.f,0.f);
  }

  const float* knp = knew + (size_t)(b*HKV + h)*HD;
  const float* vnp = vnew + (size_t)(b*HKV + h)*HD;
  const int btbase = b * MAXB;

  auto loadG = [&](float4 (&kr)[2], float4 (&vr)[2], const int blk, const int pos) {
    const int s = pos + tg;
    const float* kp = k_cache + ((size_t)blk*BS + (s & 15))*(HKV*HD) + (size_t)h*HD;
    const float* vp = v_cache + ((size_t)blk*BS + (s & 15))*(HKV*HD) + (size_t)h*HD;
    if (s == last) { kp = knp; vp = vnp; }  // token written this step -> k/v inputs
    kr[0] = *(const float4*)(kp + tl*4);
    kr[1] = *(const float4*)(kp + 64 + tl*4);
    vr[0] = *(const float4*)(vp + tl*4);
    vr[1] = *(const float4*)(vp + 64 + tl*4);
  };

  auto computeG = [&](const float4 (&kr)[2], const float4 (&vr)[2], const int pos) {
    const bool valid = (pos + tg) < s1;
    float sc[G];
#pragma unroll
    for (int j = 0; j < G; ++j) {
      float p = dot8(q0[j], q1[j], kr[0], kr[1]);
      p = row_reduce_add(p);                  // VALU-only 16-lane reduce
      sc[j] = valid ? p * SCALE : NEGI;
    }
    bool need = false;
#pragma unroll
    for (int j = 0; j < G; ++j) need = need || (sc[j] > m[j] + RESCALE_THR);
    if (__any(need)) {
#pragma unroll
      for (int j = 0; j < G; ++j) {
        const float mn = fmaxf(m[j], sc[j]);
        const float f  = __expf(m[j] - mn);
        l[j] *= f;
        a0[j].x *= f; a0[j].y *= f; a0[j].z *= f; a0[j].w *= f;
        a1[j].x *= f; a1[j].y *= f; a1[j].z *= f; a1[j].w *= f;
        m[j] = mn;
      }
    }
#pragma unroll
    for (int j = 0; j < G; ++j) {
      const float pp = __expf(sc[j] - m[j]);  // bounded by e^THR; 0 for invalid
      l[j] += pp;
      a0[j].x += pp*vr[0].x; a0[j].y += pp*vr[0].y;
      a0[j].z += pp*vr[0].z; a0[j].w += pp*vr[0].w;
      a1[j].x += pp*vr[1].x; a1[j].y += pp*vr[1].y;
      a1[j].z += pp*vr[1].z; a1[j].w += pp*vr[1].w;
    }
  };

  // ---- rotating 4-buffer pipeline: compute(g) || load(g+4)  (r9, 105us) ----
  {
    const int npos   = s1 - s0;
    const int npages = (npos + 15) >> 4;
    const int pg0    = s0 >> 4;

    float4 kA[2], vA[2], kB[2], vB[2], kC[2], vC[2], kD[2], vD[2];

    int blkCur  = block_tables[btbase + pg0];
    int blkNext = block_tables[btbase + pg0 + ((npages > 1) ? 1 : 0)];

    loadG(kA, vA, blkCur, s0);
    loadG(kB, vB, blkCur, s0 + 4);
    loadG(kC, vC, blkCur, s0 + 8);
    loadG(kD, vD, blkCur, s0 + 12);

    for (int p = 0; p < npages; ++p) {
      const int base  = s0 + p*16;
      const bool more = (p + 1 < npages);
      const int blkL  = blkNext;
      const int lbase = base + 16;
      const int pnn   = (p + 2 < npages) ? (p + 2) : (npages - 1);
      const int blkNN = block_tables[btbase + pg0 + pnn];

      computeG(kA, vA, base);
      if (more) loadG(kA, vA, blkL, lbase);
      computeG(kB, vB, base + 4);
      if (more) loadG(kB, vB, blkL, lbase + 4);
      computeG(kC, vC, base + 8);
      if (more) loadG(kC, vC, blkL, lbase + 8);
      computeG(kD, vD, base + 12);
      if (more) loadG(kD, vD, blkL, lbase + 12);

      blkNext = blkNN;
    }
  }

  // ---- combine the 4 tg partials (butterfly xor 16, 32) ----
#pragma unroll
  for (int mask = 16; mask <= 32; mask <<= 1) {
#pragma unroll
    for (int j = 0; j < G; ++j) {
      const float mo = __shfl_xor(m[j], mask, 64);
      const float lo = __shfl_xor(l[j], mask, 64);
      const float mn = fmaxf(m[j], mo);
      const float f0 = __expf(m[j] - mn);
      const float f1 = __expf(mo  - mn);
      l[j] = l[j]*f0 + lo*f1;
      float t;
      t = __shfl_xor(a0[j].x, mask, 64); a0[j].x = a0[j].x*f0 + t*f1;
      t = __shfl_xor(a0[j].y, mask, 64); a0[j].y = a0[j].y*f0 + t*f1;
      t = __shfl_xor(a0[j].z, mask, 64); a0[j].z = a0[j].z*f0 + t*f1;
      t = __shfl_xor(a0[j].w, mask, 64); a0[j].w = a0[j].w*f0 + t*f1;
      t = __shfl_xor(a1[j].x, mask, 64); a1[j].x = a1[j].x*f0 + t*f1;
      t = __shfl_xor(a1[j].y, mask, 64); a1[j].y = a1[j].y*f0 + t*f1;
      t = __shfl_xor(a1[j].z, mask, 64); a1[j].z = a1[j].z*f0 + t*f1;
      t = __shfl_xor(a1[j].w, mask, 64); a1[j].w = a1[j].w*f0 + t*f1;
      m[j] = mn;
    }
  }

  if (tg == 0) {
    if (tl == 0) {
#pragma unroll
      for (int j = 0; j < G; ++j) {
        part_ml[(pidx*G + j)*2 + 0] = m[j];
        part_ml[(pidx*G + j)*2 + 1] = l[j];
      }
    }
#pragma unroll
    for (int j = 0; j < G; ++j) {
      *(float4*)(part_acc + (pidx*G + j)*HD + tl*4)      = a0[j];
      *(float4*)(part_acc + (pidx*G + j)*HD + 64 + tl*4) = a1[j];
    }
  }

  // ---- fused final reduction: last block of (b,hg) reduces to d_out ----
  __threadfence();                       // release partials device-wide (cross-XCD)
  __syncthreads();                       // whole block fenced
  __shared__ int is_last;
  if (threadIdx.x == 0)
    is_last = (atomicAdd(&cnt[b*2 + hg], 1) == NSPLIT*1 - 1) ? 1 : 0;
  __syncthreads();
  if (!is_last) return;
  __threadfence();                       // acquire other blocks' partials

  // 256 threads -> 16 q-heads x 16 dim-groups (8 dims each)
  const int qi = threadIdx.x >> 4;       // 0..15: w = qi>>2, j = qi&3
  const int t2 = threadIdx.x & 15;
  const int hh = hg*4 + (qi >> 2);
  const int jj = qi & 3;
  const size_t rbase = (size_t)(b*HKV + hh)*NSPLIT;
  const int d0 = t2*8;

  float mg = NEGF;
  for (int p = 0; p < NSPLIT; ++p)
    mg = fmaxf(mg, part_ml[((rbase + p)*G + jj)*2 + 0]);

  float ls = 0.f;
  float4 s0v = make_float4(0.f,0.f,0.f,0.f);
  float4 s1v = make_float4(0.f,0.f,0.f,0.f);
  for (int p = 0; p < NSPLIT; ++p) {
    const float mm = part_ml[((rbase + p)*G + jj)*2 + 0];
    const float ll = part_ml[((rbase + p)*G + jj)*2 + 1];
    const float f  = __expf(mm - mg);
    ls += f * ll;
    const float* ap = part_acc + ((rbase + p)*G + jj)*HD + d0;
    const float4 x0 = *(const float4*)(ap);
    const float4 x1 = *(const float4*)(ap + 4);
    s0v.x += f*x0.x; s0v.y += f*x0.y; s0v.z += f*x0.z; s0v.w += f*x0.w;
    s1v.x += f*x1.x; s1v.y += f*x1.y; s1v.z += f*x1.z; s1v.w += f*x1.w;
  }
  const float inv = 1.f / ls;
  float* op = out + (size_t)(b*HQ + hh*G + jj)*HD + d0;
  *(float4*)(op)     = make_float4(s0v.x*inv, s0v.y*inv, s0v.z*inv, s0v.w*inv);
  *(float4*)(op + 4) = make_float4(s1v.x*inv, s1v.y*inv, s1v.z*inv, s1v.w*inv);
}

extern "C" void kernel_launch(void* const* d_in, const int* in_sizes, int n_in,
                              void* d_out, int out_size, void* d_ws, size_t ws_size,
                              hipStream_t stream) {
  const float* q  = (const float*)d_in[0];
  const float* k  = (const float*)d_in[1];
  const float* v  = (const float*)d_in[2];
  const float* kc = (const float*)d_in[3];
  const float* vc = (const float*)d_in[4];
  // d_in[5] = slot_mapping (unused: it addresses logical position seq_len-1)
  const int* bt = (const int*)d_in[6];
  const int* sl = (const int*)d_in[7];
  // d_in[8] = query_lens (all 1), d_in[9] = is_prefill (False) — unused

  int*   cnt      = (int*)d_ws;                       // 32 counters (256B pad)
  float* part_ml  = (float*)((char*)d_ws + 256);
  float* part_acc = part_ml + (size_t)NBATCH * HKV * NSPLIT * G * 2;

  // zero the arrival counters each call (graph-capturable stream op)
  hipMemsetAsync(cnt, 0, NBATCH * 2 * sizeof(int), stream);

  hipLaunchKernelGGL(pa_split, dim3(NBATCH * NSPLIT * 2), dim3(256), 0, stream,
                     q, k, v, kc, vc, bt, sl, cnt, part_ml, part_acc, (float*)d_out);
}